// Round 8
// baseline (311.157 us; speedup 1.0000x reference)
//
#include <hip/hip_runtime.h>
#include <hip/hip_bf16.h>
#include <stdint.h>

// OldQuantLinear: y = x @ (scales.T * unpack4(qweight) - zeros.T) + bias
// R8: R7 structure (pre-dequant + 256x256 BK=32 4-deep-ring bf16 GEMM, 1
// barrier/K-tile, counted vmcnt, swizzled LDS) with MFMA shape switched to
// 32x32x16 (µbench ceiling 2495 vs 2176 TF; half the MFMA instructions).
// Wave-tile 128x64 = 4x2 frags of 32x32; per K-tile: 2 k-steps x 8 MFMA.
// LDS layout invariant unchanged: granule (row, sp) holds kb = sp ^ ((row>>1)&3).
// C/D layout (verified m74/m101): col = lane&31, row = (reg&3)+8*(reg>>2)+4*(lane>>5).

#define BM 256
#define BN 256
#define BK 32
#define NBUF 4

using f32x4   = __attribute__((ext_vector_type(4))) float;
using f32x16  = __attribute__((ext_vector_type(16))) float;
using bf16x8  = __attribute__((ext_vector_type(8))) __bf16;

typedef const uint32_t __attribute__((address_space(1)))* gas_ptr;
typedef uint32_t __attribute__((address_space(3)))* las_ptr;

__device__ __forceinline__ void gl16(const __bf16* g, __bf16* l) {
    __builtin_amdgcn_global_load_lds((gas_ptr)g, (las_ptr)l, 16, 0, 0);
}

// ---------------- pre-pass 1: x f32 -> bf16 ----------------
__global__ __launch_bounds__(256) void cvt_x_kernel(
    const float* __restrict__ x, __bf16* __restrict__ xb, size_t n8)
{
    size_t i = (size_t)blockIdx.x * 256 + threadIdx.x;
    if (i >= n8) return;
    const f32x4* p = (const f32x4*)(x + i * 8);
    f32x4 a = p[0], b = p[1];
    bf16x8 v;
    v[0] = (__bf16)a[0]; v[1] = (__bf16)a[1]; v[2] = (__bf16)a[2]; v[3] = (__bf16)a[3];
    v[4] = (__bf16)b[0]; v[5] = (__bf16)b[1]; v[6] = (__bf16)b[2]; v[7] = (__bf16)b[3];
    *(bf16x8*)(xb + i * 8) = v;
}

// ---------------- pre-pass 2: qweight -> Wt [N][K] bf16 ----------------
__global__ __launch_bounds__(256) void dequant_w_kernel(
    const int* __restrict__ qw, const float* __restrict__ scales,
    const float* __restrict__ zeros, __bf16* __restrict__ Wt, int N, int K)
{
    __shared__ __align__(16) __bf16 T[64 * 32 * 8];
    const int tid = threadIdx.x;
    const int nTilesN = N >> 6;
    const int kg0 = (blockIdx.x / nTilesN) << 5;
    const int n0  = (blockIdx.x % nTilesN) << 6;

    #pragma unroll
    for (int it = 0; it < 8; ++it) {
        int idx  = it * 256 + tid;
        int kg_l = idx >> 6, n_l = idx & 63;
        int n = n0 + n_l;
        float s = scales[n], nz = -zeros[n];
        uint32_t w  = (uint32_t)qw[(size_t)(kg0 + kg_l) * N + n];
        uint32_t lo = w & 0x0F0F0F0Fu;
        uint32_t hi = (w >> 4) & 0x0F0F0F0Fu;
        bf16x8 v;
        v[0] = (__bf16)fmaf(s, (float)(lo & 0xFFu),         nz);
        v[1] = (__bf16)fmaf(s, (float)(hi & 0xFFu),         nz);
        v[2] = (__bf16)fmaf(s, (float)((lo >> 8)  & 0xFFu), nz);
        v[3] = (__bf16)fmaf(s, (float)((hi >> 8)  & 0xFFu), nz);
        v[4] = (__bf16)fmaf(s, (float)((lo >> 16) & 0xFFu), nz);
        v[5] = (__bf16)fmaf(s, (float)((hi >> 16) & 0xFFu), nz);
        v[6] = (__bf16)fmaf(s, (float)(lo >> 24),           nz);
        v[7] = (__bf16)fmaf(s, (float)(hi >> 24),           nz);
        int slot = kg_l ^ (n_l & 7);
        *(bf16x8*)&T[(size_t)(n_l * 32 + slot) * 8] = v;
    }
    __syncthreads();
    #pragma unroll
    for (int it = 0; it < 8; ++it) {
        int idx  = it * 256 + tid;
        int n_l  = idx >> 5, kg_l = idx & 31;
        bf16x8 v = *(const bf16x8*)&T[(size_t)(n_l * 32 + (kg_l ^ (n_l & 7))) * 8];
        *(bf16x8*)&Wt[(size_t)(n0 + n_l) * K + (size_t)(kg0 + kg_l) * 8] = v;
    }
}

// ---------------- main GEMM: 256x256, 8 waves, 4-ring, 32x32x16 MFMA ----
__global__ __launch_bounds__(512) void qgemm8_kernel(
    const __bf16* __restrict__ A, const __bf16* __restrict__ Bt,
    const float* __restrict__ bias, float* __restrict__ out,
    int M, int N, int K)
{
    __shared__ __align__(16) __bf16 Alds[NBUF * BM * BK];  // 64 KiB
    __shared__ __align__(16) __bf16 Blds[NBUF * BN * BK];  // 64 KiB

    const int tid = threadIdx.x;
    const int l   = tid & 63;
    const int w   = tid >> 6;
    const int wm  = w >> 2;        // 0..1 (M half, 128 rows)
    const int wn  = w & 3;         // 0..3 (N quarter, 64 cols)
    const int l31 = l & 31;
    const int lk  = l >> 5;        // 0..1 (k-half within fragment)

    // T1: bijective XCD swizzle (nwg % 8 == 0 for our shapes)
    int bid = (int)blockIdx.x;
    const int nwg = (int)gridDim.x;
    if ((nwg & 7) == 0) bid = (bid & 7) * (nwg >> 3) + (bid >> 3);

    const int nTilesN = N / BN;
    const int brow = (bid / nTilesN) * BM;
    const int bcol = (bid % nTilesN) * BN;

    // staging (unchanged from R7, proven 0-conflict):
    //   gi = w*128 + j*64 + l ; row = w*32 + j*16 + (l>>2); slot_pos = l&3
    //   k-granule kb = (l&3) ^ ((l>>3)&3)
    const int skb  = (l & 3) ^ ((l >> 3) & 3);
    const int srow = w * 32 + (l >> 2);
    const __bf16* aS0 = A  + (size_t)(brow + srow) * K + skb * 8;
    const __bf16* aS1 = aS0 + (size_t)16 * K;
    const __bf16* bS0 = Bt + (size_t)(bcol + srow) * K + skb * 8;
    const __bf16* bS1 = bS0 + (size_t)16 * K;
    __bf16* aD0 = &Alds[(w * 128) * 8];       // wave-uniform; HW adds lane*16B
    __bf16* aD1 = &Alds[(w * 128 + 64) * 8];
    __bf16* bD0 = &Blds[(w * 128) * 8];
    __bf16* bD1 = &Blds[(w * 128 + 64) * 8];

    #define STAGE_A(tt) { const size_t ko = (size_t)(tt) * BK;            \
        const int sb = ((tt) & 3) * (BM * BK);                            \
        gl16(aS0 + ko, aD0 + sb); gl16(aS1 + ko, aD1 + sb); }
    #define STAGE_B(tt) { const size_t ko = (size_t)(tt) * BK;            \
        const int sb = ((tt) & 3) * (BN * BK);                            \
        gl16(bS0 + ko, bD0 + sb); gl16(bS1 + ko, bD1 + sb); }

    f32x16 acc[4][2];
    #pragma unroll
    for (int i = 0; i < 4; ++i)
        #pragma unroll
        for (int j = 0; j < 2; ++j)
            acc[i][j] = (f32x16)(0.f);

    const int NT = K / BK;

    // fragment read addressing (32x32x16): row = base + l31, kg = ks*2 + lk,
    // slot = kg ^ ((row>>1)&3); (row>>1)&3 == (l31>>1)&3 (bases are mult of 32).
    const int rsw  = (l31 >> 1) & 3;
    const int rsp0 = (0 * 2 + lk) ^ rsw;      // ks = 0
    const int rsp1 = (1 * 2 + lk) ^ rsw;      // ks = 1
    const int arow = wm * 128 + l31;          // + mf*32
    const int brow_f = wn * 64 + l31;         // + nf*32

    // prologue: stage tiles 0,1,2; wait own tile-0 loads; join
    STAGE_A(0); STAGE_B(0);
    STAGE_A(1); STAGE_B(1);
    STAGE_A(2); STAGE_B(2);
    asm volatile("s_waitcnt vmcnt(8)" ::: "memory");
    __builtin_amdgcn_s_barrier();

    for (int t = 0; t < NT; ++t) {
        const int bo = (t & 3) * (BM * BK);
        const bool pre = (t + 3 < NT);
        bf16x8 af[4], bfr[2];

        __builtin_amdgcn_sched_barrier(0);   // nothing crosses the barrier from below

        // ---- half 1: k-step 0 (8 MFMA of 32x32x16) ----
        #pragma unroll
        for (int mf = 0; mf < 4; ++mf)
            af[mf] = *(const bf16x8*)&Alds[bo + (arow + mf * 32) * BK + rsp0 * 8];
        #pragma unroll
        for (int nf = 0; nf < 2; ++nf)
            bfr[nf] = *(const bf16x8*)&Blds[bo + (brow_f + nf * 32) * BK + rsp0 * 8];
        if (pre) STAGE_A(t + 3);
        __builtin_amdgcn_s_setprio(1);
        #pragma unroll
        for (int mf = 0; mf < 4; ++mf)
            #pragma unroll
            for (int nf = 0; nf < 2; ++nf)
                acc[mf][nf] = __builtin_amdgcn_mfma_f32_32x32x16_bf16(
                    af[mf], bfr[nf], acc[mf][nf], 0, 0, 0);
        __builtin_amdgcn_s_setprio(0);

        // ---- half 2: k-step 1 ----
        #pragma unroll
        for (int mf = 0; mf < 4; ++mf)
            af[mf] = *(const bf16x8*)&Alds[bo + (arow + mf * 32) * BK + rsp1 * 8];
        #pragma unroll
        for (int nf = 0; nf < 2; ++nf)
            bfr[nf] = *(const bf16x8*)&Blds[bo + (brow_f + nf * 32) * BK + rsp1 * 8];
        if (pre) STAGE_B(t + 3);
        __builtin_amdgcn_s_setprio(1);
        #pragma unroll
        for (int mf = 0; mf < 4; ++mf)
            #pragma unroll
            for (int nf = 0; nf < 2; ++nf)
                acc[mf][nf] = __builtin_amdgcn_mfma_f32_32x32x16_bf16(
                    af[mf], bfr[nf], acc[mf][nf], 0, 0, 0);
        __builtin_amdgcn_s_setprio(0);

        // counted vmcnt: retire exactly tile t+1's 4 loads
        if (pre)              { asm volatile("s_waitcnt vmcnt(8)" ::: "memory"); }
        else if (t + 2 < NT)  { asm volatile("s_waitcnt vmcnt(4)" ::: "memory"); }
        else                  { asm volatile("s_waitcnt vmcnt(0)" ::: "memory"); }
        __builtin_amdgcn_sched_barrier(0);   // nothing crosses from above
        __builtin_amdgcn_s_barrier();        // ONE barrier per K-tile
    }

    // ---- epilogue: 32x32 C/D layout: col = l31, row = (r&3)+8*(r>>2)+4*lk ----
    #pragma unroll
    for (int nf = 0; nf < 2; ++nf) {
        int col = bcol + wn * 64 + nf * 32 + l31;
        float bv = bias[col];
        #pragma unroll
        for (int mf = 0; mf < 4; ++mf) {
            int row0 = brow + wm * 128 + mf * 32 + 4 * lk;
            #pragma unroll
            for (int r = 0; r < 16; ++r) {
                int row = row0 + (r & 3) + 8 * (r >> 2);
                out[(size_t)row * N + col] = acc[mf][nf][r] + bv;
            }
        }
    }
    #undef STAGE_A
    #undef STAGE_B
}

// ---------------- fallback: fused kernel (R2) ----------------
#define FT_M 128
#define FT_N 128
#define FT_K 64
__global__ __launch_bounds__(256) void qgemm_fused_kernel(
    const float* __restrict__ x, const int* __restrict__ qw,
    const float* __restrict__ scales, const float* __restrict__ zeros,
    const float* __restrict__ bias, float* __restrict__ out,
    int M, int N, int K)
{
    __shared__ __align__(16) __bf16 Alds[FT_M * FT_K];
    __shared__ __align__(16) __bf16 Blds[FT_N * FT_K];

    const int tid  = threadIdx.x;
    const int lane = tid & 63;
    const int wave = tid >> 6;
    const int wm = wave >> 1, wn = wave & 1;
    const int lrow = lane & 15, lkb = lane >> 4;

    const int nTilesN = N / FT_N;
    const int brow = (blockIdx.x / nTilesN) * FT_M;
    const int bcol = (blockIdx.x % nTilesN) * FT_N;

    const int bc  = tid & 127;
    const int qr0 = tid >> 7;
    const float s  = scales[bcol + bc];
    const float nz = -zeros[bcol + bc];

    f32x4 acc[4][4];
    #pragma unroll
    for (int i = 0; i < 4; ++i)
        #pragma unroll
        for (int j = 0; j < 4; ++j)
            acc[i][j] = (f32x4){0.f, 0.f, 0.f, 0.f};

    for (int kt = 0; kt < K; kt += FT_K) {
        #pragma unroll
        for (int i = 0; i < 4; ++i) {
            int g  = tid + i * 256;
            int r  = g >> 3;
            int kbg = g & 7;
            const float* p = x + (size_t)(brow + r) * K + kt + kbg * 8;
            f32x4 f0 = *(const f32x4*)p;
            f32x4 f1 = *(const f32x4*)(p + 4);
            bf16x8 v;
            v[0] = (__bf16)f0[0]; v[1] = (__bf16)f0[1];
            v[2] = (__bf16)f0[2]; v[3] = (__bf16)f0[3];
            v[4] = (__bf16)f1[0]; v[5] = (__bf16)f1[1];
            v[6] = (__bf16)f1[2]; v[7] = (__bf16)f1[3];
            int slot = kbg ^ (r & 7);
            *(bf16x8*)&Alds[r * FT_K + slot * 8] = v;
        }
        #pragma unroll
        for (int i = 0; i < 4; ++i) {
            int qr = qr0 + i * 2;
            uint32_t wv = (uint32_t)qw[(size_t)(kt / 8 + qr) * N + bcol + bc];
            uint32_t lo = wv & 0x0F0F0F0Fu;
            uint32_t hi = (wv >> 4) & 0x0F0F0F0Fu;
            bf16x8 v;
            v[0] = (__bf16)fmaf(s, (float)(lo & 0xFFu),         nz);
            v[1] = (__bf16)fmaf(s, (float)(hi & 0xFFu),         nz);
            v[2] = (__bf16)fmaf(s, (float)((lo >> 8)  & 0xFFu), nz);
            v[3] = (__bf16)fmaf(s, (float)((hi >> 8)  & 0xFFu), nz);
            v[4] = (__bf16)fmaf(s, (float)((lo >> 16) & 0xFFu), nz);
            v[5] = (__bf16)fmaf(s, (float)((hi >> 16) & 0xFFu), nz);
            v[6] = (__bf16)fmaf(s, (float)(lo >> 24),           nz);
            v[7] = (__bf16)fmaf(s, (float)(hi >> 24),           nz);
            int slot = qr ^ (bc & 7);
            *(bf16x8*)&Blds[bc * FT_K + slot * 8] = v;
        }
        __syncthreads();

        #pragma unroll
        for (int ks = 0; ks < 2; ++ks) {
            const int slot = (ks * 4 + lkb) ^ (lrow & 7);
            const int abase = (wm * 64 + lrow) * FT_K + slot * 8;
            const int bbase = (wn * 64 + lrow) * FT_K + slot * 8;
            bf16x8 af[4], bfr[4];
            #pragma unroll
            for (int mf = 0; mf < 4; ++mf)
                af[mf] = *(const bf16x8*)&Alds[abase + mf * 16 * FT_K];
            #pragma unroll
            for (int nf = 0; nf < 4; ++nf)
                bfr[nf] = *(const bf16x8*)&Blds[bbase + nf * 16 * FT_K];
            #pragma unroll
            for (int mf = 0; mf < 4; ++mf)
                #pragma unroll
                for (int nf = 0; nf < 4; ++nf)
                    acc[mf][nf] = __builtin_amdgcn_mfma_f32_16x16x32_bf16(
                        af[mf], bfr[nf], acc[mf][nf], 0, 0, 0);
        }
        __syncthreads();
    }

    #pragma unroll
    for (int nf = 0; nf < 4; ++nf) {
        int col = bcol + wn * 64 + nf * 16 + lrow;
        float bv = bias[col];
        #pragma unroll
        for (int mf = 0; mf < 4; ++mf) {
            int row = brow + wm * 64 + mf * 16 + lkb * 4;
            #pragma unroll
            for (int i = 0; i < 4; ++i)
                out[(size_t)(row + i) * N + col] = acc[mf][nf][i] + bv;
        }
    }
}

extern "C" void kernel_launch(void* const* d_in, const int* in_sizes, int n_in,
                              void* d_out, int out_size, void* d_ws, size_t ws_size,
                              hipStream_t stream) {
    const float* x      = (const float*)d_in[0];
    const int*   qw     = (const int*)d_in[1];
    const float* scales = (const float*)d_in[2];
    const float* zeros  = (const float*)d_in[3];
    const float* bias   = (const float*)d_in[4];
    float* out = (float*)d_out;

    const int N = in_sizes[4];                              // OUT
    const int K = (int)(((long long)in_sizes[1] * 8) / N);  // IN
    const int M = in_sizes[0] / K;

    const size_t xb_elems = (size_t)M * K;
    const size_t wt_elems = (size_t)N * K;
    const size_t need = (xb_elems + wt_elems) * sizeof(__bf16);

    const bool shapes_ok = (M % BM == 0) && (N % BN == 0) && (K % 256 == 0) &&
                           (K / BK >= 4);

    if (ws_size >= need && shapes_ok) {
        __bf16* xb = (__bf16*)d_ws;
        __bf16* Wt = xb + xb_elems;

        size_t n8 = xb_elems / 8;
        cvt_x_kernel<<<dim3((unsigned)((n8 + 255) / 256)), 256, 0, stream>>>(x, xb, n8);

        dim3 dq_grid((unsigned)(((K / 8) / 32) * (N / 64)));
        dequant_w_kernel<<<dq_grid, 256, 0, stream>>>(qw, scales, zeros, Wt, N, K);

        dim3 grid((M / BM) * (N / BN));
        qgemm8_kernel<<<grid, 512, 0, stream>>>(xb, Wt, bias, out, M, N, K);
    } else {
        dim3 grid((M / FT_M) * (N / FT_N));
        qgemm_fused_kernel<<<grid, 256, 0, stream>>>(x, qw, scales, zeros, bias, out, M, N, K);
    }
}

// Round 9
// 309.538 us; speedup vs baseline: 1.0052x; 1.0052x over previous
//
#include <hip/hip_runtime.h>
#include <hip/hip_bf16.h>
#include <stdint.h>

// OldQuantLinear: y = x @ (scales.T * unpack4(qweight) - zeros.T) + bias
// R9: R8 (256x256 BK=32 4-ring, 32x32x16 MFMA, 1 barrier/tile) with the LDS
// content swizzle extended to kill the 32x32-fragment bank conflicts:
//   granule (row, sp) holds k-granule kb = sp ^ f(row),
//   f(row) = ((row>>1)&3) ^ ((row>>3)&3)       <- new row-bit-3 term
// Stage (linear LDS dest, swizzled global source, per-instr j):
//   skb_j = (l&3) ^ ((l>>3)&3) ^ ((j*2 + (l>>5))&3)
// Read: rsw = ((l31>>1)&3) ^ ((l31>>3)&3)  (mf/nf-invariant; bases mult of 32)
// R8 measured 2.517e7 conflicts from same-slot lane pairs at dlane=8/16 within
// one k-half; the bit-3 XOR breaks all of them.

#define BM 256
#define BN 256
#define BK 32
#define NBUF 4

using f32x4   = __attribute__((ext_vector_type(4))) float;
using f32x16  = __attribute__((ext_vector_type(16))) float;
using bf16x8  = __attribute__((ext_vector_type(8))) __bf16;

typedef const uint32_t __attribute__((address_space(1)))* gas_ptr;
typedef uint32_t __attribute__((address_space(3)))* las_ptr;

__device__ __forceinline__ void gl16(const __bf16* g, __bf16* l) {
    __builtin_amdgcn_global_load_lds((gas_ptr)g, (las_ptr)l, 16, 0, 0);
}

// ---------------- pre-pass 1: x f32 -> bf16 ----------------
__global__ __launch_bounds__(256) void cvt_x_kernel(
    const float* __restrict__ x, __bf16* __restrict__ xb, size_t n8)
{
    size_t i = (size_t)blockIdx.x * 256 + threadIdx.x;
    if (i >= n8) return;
    const f32x4* p = (const f32x4*)(x + i * 8);
    f32x4 a = p[0], b = p[1];
    bf16x8 v;
    v[0] = (__bf16)a[0]; v[1] = (__bf16)a[1]; v[2] = (__bf16)a[2]; v[3] = (__bf16)a[3];
    v[4] = (__bf16)b[0]; v[5] = (__bf16)b[1]; v[6] = (__bf16)b[2]; v[7] = (__bf16)b[3];
    *(bf16x8*)(xb + i * 8) = v;
}

// ---------------- pre-pass 2: qweight -> Wt [N][K] bf16 ----------------
__global__ __launch_bounds__(256) void dequant_w_kernel(
    const int* __restrict__ qw, const float* __restrict__ scales,
    const float* __restrict__ zeros, __bf16* __restrict__ Wt, int N, int K)
{
    __shared__ __align__(16) __bf16 T[64 * 32 * 8];
    const int tid = threadIdx.x;
    const int nTilesN = N >> 6;
    const int kg0 = (blockIdx.x / nTilesN) << 5;
    const int n0  = (blockIdx.x % nTilesN) << 6;

    #pragma unroll
    for (int it = 0; it < 8; ++it) {
        int idx  = it * 256 + tid;
        int kg_l = idx >> 6, n_l = idx & 63;
        int n = n0 + n_l;
        float s = scales[n], nz = -zeros[n];
        uint32_t w  = (uint32_t)qw[(size_t)(kg0 + kg_l) * N + n];
        uint32_t lo = w & 0x0F0F0F0Fu;
        uint32_t hi = (w >> 4) & 0x0F0F0F0Fu;
        bf16x8 v;
        v[0] = (__bf16)fmaf(s, (float)(lo & 0xFFu),         nz);
        v[1] = (__bf16)fmaf(s, (float)(hi & 0xFFu),         nz);
        v[2] = (__bf16)fmaf(s, (float)((lo >> 8)  & 0xFFu), nz);
        v[3] = (__bf16)fmaf(s, (float)((hi >> 8)  & 0xFFu), nz);
        v[4] = (__bf16)fmaf(s, (float)((lo >> 16) & 0xFFu), nz);
        v[5] = (__bf16)fmaf(s, (float)((hi >> 16) & 0xFFu), nz);
        v[6] = (__bf16)fmaf(s, (float)(lo >> 24),           nz);
        v[7] = (__bf16)fmaf(s, (float)(hi >> 24),           nz);
        int slot = kg_l ^ (n_l & 7);
        *(bf16x8*)&T[(size_t)(n_l * 32 + slot) * 8] = v;
    }
    __syncthreads();
    #pragma unroll
    for (int it = 0; it < 8; ++it) {
        int idx  = it * 256 + tid;
        int n_l  = idx >> 5, kg_l = idx & 31;
        bf16x8 v = *(const bf16x8*)&T[(size_t)(n_l * 32 + (kg_l ^ (n_l & 7))) * 8];
        *(bf16x8*)&Wt[(size_t)(n0 + n_l) * K + (size_t)(kg0 + kg_l) * 8] = v;
    }
}

// ---------------- main GEMM: 256x256, 8 waves, 4-ring, 32x32x16 MFMA ----
__global__ __launch_bounds__(512) void qgemm8_kernel(
    const __bf16* __restrict__ A, const __bf16* __restrict__ Bt,
    const float* __restrict__ bias, float* __restrict__ out,
    int M, int N, int K)
{
    __shared__ __align__(16) __bf16 Alds[NBUF * BM * BK];  // 64 KiB
    __shared__ __align__(16) __bf16 Blds[NBUF * BN * BK];  // 64 KiB

    const int tid = threadIdx.x;
    const int l   = tid & 63;
    const int w   = tid >> 6;
    const int wm  = w >> 2;        // 0..1 (M half, 128 rows)
    const int wn  = w & 3;         // 0..3 (N quarter, 64 cols)
    const int l31 = l & 31;
    const int lk  = l >> 5;        // 0..1 (k-half within fragment)

    // T1: bijective XCD swizzle (nwg % 8 == 0 for our shapes)
    int bid = (int)blockIdx.x;
    const int nwg = (int)gridDim.x;
    if ((nwg & 7) == 0) bid = (bid & 7) * (nwg >> 3) + (bid >> 3);

    const int nTilesN = N / BN;
    const int brow = (bid / nTilesN) * BM;
    const int bcol = (bid % nTilesN) * BN;

    // staging: gi = w*128 + j*64 + l; row = w*32 + j*16 + (l>>2); sp = l&3
    // content kb = sp ^ f(row), f(row) = ((row>>1)&3) ^ ((row>>3)&3)
    //   -> skb_j = (l&3) ^ ((l>>3)&3) ^ ((j*2 + (l>>5))&3)
    const int skb0 = (l & 3) ^ ((l >> 3) & 3) ^ ((l >> 5) & 3);
    const int skb1 = (l & 3) ^ ((l >> 3) & 3) ^ ((2 + (l >> 5)) & 3);
    const int srow = w * 32 + (l >> 2);
    const __bf16* aS0 = A  + (size_t)(brow + srow) * K + skb0 * 8;
    const __bf16* aS1 = A  + (size_t)(brow + srow + 16) * K + skb1 * 8;
    const __bf16* bS0 = Bt + (size_t)(bcol + srow) * K + skb0 * 8;
    const __bf16* bS1 = Bt + (size_t)(bcol + srow + 16) * K + skb1 * 8;
    __bf16* aD0 = &Alds[(w * 128) * 8];       // wave-uniform; HW adds lane*16B
    __bf16* aD1 = &Alds[(w * 128 + 64) * 8];
    __bf16* bD0 = &Blds[(w * 128) * 8];
    __bf16* bD1 = &Blds[(w * 128 + 64) * 8];

    #define STAGE_A(tt) { const size_t ko = (size_t)(tt) * BK;            \
        const int sb = ((tt) & 3) * (BM * BK);                            \
        gl16(aS0 + ko, aD0 + sb); gl16(aS1 + ko, aD1 + sb); }
    #define STAGE_B(tt) { const size_t ko = (size_t)(tt) * BK;            \
        const int sb = ((tt) & 3) * (BN * BK);                            \
        gl16(bS0 + ko, bD0 + sb); gl16(bS1 + ko, bD1 + sb); }

    f32x16 acc[4][2];
    #pragma unroll
    for (int i = 0; i < 4; ++i)
        #pragma unroll
        for (int j = 0; j < 2; ++j)
            acc[i][j] = (f32x16)(0.f);

    const int NT = K / BK;

    // read: row = base + l31 (bases mult of 32) -> f(row) = rsw below
    const int rsw  = ((l31 >> 1) & 3) ^ ((l31 >> 3) & 3);
    const int rsp0 = lk ^ rsw;                // ks = 0: kb = lk
    const int rsp1 = (2 + lk) ^ rsw;          // ks = 1: kb = 2 + lk
    const int arow   = wm * 128 + l31;        // + mf*32
    const int brow_f = wn * 64 + l31;         // + nf*32

    // prologue: stage tiles 0,1,2; wait own tile-0 loads; join
    STAGE_A(0); STAGE_B(0);
    STAGE_A(1); STAGE_B(1);
    STAGE_A(2); STAGE_B(2);
    asm volatile("s_waitcnt vmcnt(8)" ::: "memory");
    __builtin_amdgcn_s_barrier();

    for (int t = 0; t < NT; ++t) {
        const int bo = (t & 3) * (BM * BK);
        const bool pre = (t + 3 < NT);
        bf16x8 af[4], bfr[2];

        __builtin_amdgcn_sched_barrier(0);   // nothing crosses the barrier from below

        // ---- half 1: k-step 0 (8 MFMA of 32x32x16) ----
        #pragma unroll
        for (int mf = 0; mf < 4; ++mf)
            af[mf] = *(const bf16x8*)&Alds[bo + (arow + mf * 32) * BK + rsp0 * 8];
        #pragma unroll
        for (int nf = 0; nf < 2; ++nf)
            bfr[nf] = *(const bf16x8*)&Blds[bo + (brow_f + nf * 32) * BK + rsp0 * 8];
        if (pre) STAGE_A(t + 3);
        __builtin_amdgcn_s_setprio(1);
        #pragma unroll
        for (int mf = 0; mf < 4; ++mf)
            #pragma unroll
            for (int nf = 0; nf < 2; ++nf)
                acc[mf][nf] = __builtin_amdgcn_mfma_f32_32x32x16_bf16(
                    af[mf], bfr[nf], acc[mf][nf], 0, 0, 0);
        __builtin_amdgcn_s_setprio(0);

        // ---- half 2: k-step 1 ----
        #pragma unroll
        for (int mf = 0; mf < 4; ++mf)
            af[mf] = *(const bf16x8*)&Alds[bo + (arow + mf * 32) * BK + rsp1 * 8];
        #pragma unroll
        for (int nf = 0; nf < 2; ++nf)
            bfr[nf] = *(const bf16x8*)&Blds[bo + (brow_f + nf * 32) * BK + rsp1 * 8];
        if (pre) STAGE_B(t + 3);
        __builtin_amdgcn_s_setprio(1);
        #pragma unroll
        for (int mf = 0; mf < 4; ++mf)
            #pragma unroll
            for (int nf = 0; nf < 2; ++nf)
                acc[mf][nf] = __builtin_amdgcn_mfma_f32_32x32x16_bf16(
                    af[mf], bfr[nf], acc[mf][nf], 0, 0, 0);
        __builtin_amdgcn_s_setprio(0);

        // counted vmcnt: retire exactly tile t+1's 4 loads
        if (pre)              { asm volatile("s_waitcnt vmcnt(8)" ::: "memory"); }
        else if (t + 2 < NT)  { asm volatile("s_waitcnt vmcnt(4)" ::: "memory"); }
        else                  { asm volatile("s_waitcnt vmcnt(0)" ::: "memory"); }
        __builtin_amdgcn_sched_barrier(0);   // nothing crosses from above
        __builtin_amdgcn_s_barrier();        // ONE barrier per K-tile
    }

    // ---- epilogue: 32x32 C/D layout: col = l31, row = (r&3)+8*(r>>2)+4*lk ----
    #pragma unroll
    for (int nf = 0; nf < 2; ++nf) {
        int col = bcol + wn * 64 + nf * 32 + l31;
        float bv = bias[col];
        #pragma unroll
        for (int mf = 0; mf < 4; ++mf) {
            int row0 = brow + wm * 128 + mf * 32 + 4 * lk;
            #pragma unroll
            for (int r = 0; r < 16; ++r) {
                int row = row0 + (r & 3) + 8 * (r >> 2);
                out[(size_t)row * N + col] = acc[mf][nf][r] + bv;
            }
        }
    }
    #undef STAGE_A
    #undef STAGE_B
}

// ---------------- fallback: fused kernel (R2) ----------------
#define FT_M 128
#define FT_N 128
#define FT_K 64
__global__ __launch_bounds__(256) void qgemm_fused_kernel(
    const float* __restrict__ x, const int* __restrict__ qw,
    const float* __restrict__ scales, const float* __restrict__ zeros,
    const float* __restrict__ bias, float* __restrict__ out,
    int M, int N, int K)
{
    __shared__ __align__(16) __bf16 Alds[FT_M * FT_K];
    __shared__ __align__(16) __bf16 Blds[FT_N * FT_K];

    const int tid  = threadIdx.x;
    const int lane = tid & 63;
    const int wave = tid >> 6;
    const int wm = wave >> 1, wn = wave & 1;
    const int lrow = lane & 15, lkb = lane >> 4;

    const int nTilesN = N / FT_N;
    const int brow = (blockIdx.x / nTilesN) * FT_M;
    const int bcol = (blockIdx.x % nTilesN) * FT_N;

    const int bc  = tid & 127;
    const int qr0 = tid >> 7;
    const float s  = scales[bcol + bc];
    const float nz = -zeros[bcol + bc];

    f32x4 acc[4][4];
    #pragma unroll
    for (int i = 0; i < 4; ++i)
        #pragma unroll
        for (int j = 0; j < 4; ++j)
            acc[i][j] = (f32x4){0.f, 0.f, 0.f, 0.f};

    for (int kt = 0; kt < K; kt += FT_K) {
        #pragma unroll
        for (int i = 0; i < 4; ++i) {
            int g  = tid + i * 256;
            int r  = g >> 3;
            int kbg = g & 7;
            const float* p = x + (size_t)(brow + r) * K + kt + kbg * 8;
            f32x4 f0 = *(const f32x4*)p;
            f32x4 f1 = *(const f32x4*)(p + 4);
            bf16x8 v;
            v[0] = (__bf16)f0[0]; v[1] = (__bf16)f0[1];
            v[2] = (__bf16)f0[2]; v[3] = (__bf16)f0[3];
            v[4] = (__bf16)f1[0]; v[5] = (__bf16)f1[1];
            v[6] = (__bf16)f1[2]; v[7] = (__bf16)f1[3];
            int slot = kbg ^ (r & 7);
            *(bf16x8*)&Alds[r * FT_K + slot * 8] = v;
        }
        #pragma unroll
        for (int i = 0; i < 4; ++i) {
            int qr = qr0 + i * 2;
            uint32_t wv = (uint32_t)qw[(size_t)(kt / 8 + qr) * N + bcol + bc];
            uint32_t lo = wv & 0x0F0F0F0Fu;
            uint32_t hi = (wv >> 4) & 0x0F0F0F0Fu;
            bf16x8 v;
            v[0] = (__bf16)fmaf(s, (float)(lo & 0xFFu),         nz);
            v[1] = (__bf16)fmaf(s, (float)(hi & 0xFFu),         nz);
            v[2] = (__bf16)fmaf(s, (float)((lo >> 8)  & 0xFFu), nz);
            v[3] = (__bf16)fmaf(s, (float)((hi >> 8)  & 0xFFu), nz);
            v[4] = (__bf16)fmaf(s, (float)((lo >> 16) & 0xFFu), nz);
            v[5] = (__bf16)fmaf(s, (float)((hi >> 16) & 0xFFu), nz);
            v[6] = (__bf16)fmaf(s, (float)(lo >> 24),           nz);
            v[7] = (__bf16)fmaf(s, (float)(hi >> 24),           nz);
            int slot = qr ^ (bc & 7);
            *(bf16x8*)&Blds[bc * FT_K + slot * 8] = v;
        }
        __syncthreads();

        #pragma unroll
        for (int ks = 0; ks < 2; ++ks) {
            const int slot = (ks * 4 + lkb) ^ (lrow & 7);
            const int abase = (wm * 64 + lrow) * FT_K + slot * 8;
            const int bbase = (wn * 64 + lrow) * FT_K + slot * 8;
            bf16x8 af[4], bfr[4];
            #pragma unroll
            for (int mf = 0; mf < 4; ++mf)
                af[mf] = *(const bf16x8*)&Alds[abase + mf * 16 * FT_K];
            #pragma unroll
            for (int nf = 0; nf < 4; ++nf)
                bfr[nf] = *(const bf16x8*)&Blds[bbase + nf * 16 * FT_K];
            #pragma unroll
            for (int mf = 0; mf < 4; ++mf)
                #pragma unroll
                for (int nf = 0; nf < 4; ++nf)
                    acc[mf][nf] = __builtin_amdgcn_mfma_f32_16x16x32_bf16(
                        af[mf], bfr[nf], acc[mf][nf], 0, 0, 0);
        }
        __syncthreads();
    }

    #pragma unroll
    for (int nf = 0; nf < 4; ++nf) {
        int col = bcol + wn * 64 + nf * 16 + lrow;
        float bv = bias[col];
        #pragma unroll
        for (int mf = 0; mf < 4; ++mf) {
            int row = brow + wm * 64 + mf * 16 + lkb * 4;
            #pragma unroll
            for (int i = 0; i < 4; ++i)
                out[(size_t)(row + i) * N + col] = acc[mf][nf][i] + bv;
        }
    }
}

extern "C" void kernel_launch(void* const* d_in, const int* in_sizes, int n_in,
                              void* d_out, int out_size, void* d_ws, size_t ws_size,
                              hipStream_t stream) {
    const float* x      = (const float*)d_in[0];
    const int*   qw     = (const int*)d_in[1];
    const float* scales = (const float*)d_in[2];
    const float* zeros  = (const float*)d_in[3];
    const float* bias   = (const float*)d_in[4];
    float* out = (float*)d_out;

    const int N = in_sizes[4];                              // OUT
    const int K = (int)(((long long)in_sizes[1] * 8) / N);  // IN
    const int M = in_sizes[0] / K;

    const size_t xb_elems = (size_t)M * K;
    const size_t wt_elems = (size_t)N * K;
    const size_t need = (xb_elems + wt_elems) * sizeof(__bf16);

    const bool shapes_ok = (M % BM == 0) && (N % BN == 0) && (K % 256 == 0) &&
                           (K / BK >= 4);

    if (ws_size >= need && shapes_ok) {
        __bf16* xb = (__bf16*)d_ws;
        __bf16* Wt = xb + xb_elems;

        size_t n8 = xb_elems / 8;
        cvt_x_kernel<<<dim3((unsigned)((n8 + 255) / 256)), 256, 0, stream>>>(x, xb, n8);

        dim3 dq_grid((unsigned)(((K / 8) / 32) * (N / 64)));
        dequant_w_kernel<<<dq_grid, 256, 0, stream>>>(qw, scales, zeros, Wt, N, K);

        dim3 grid((M / BM) * (N / BN));
        qgemm8_kernel<<<grid, 512, 0, stream>>>(xb, Wt, bias, out, M, N, K);
    } else {
        dim3 grid((M / FT_M) * (N / FT_N));
        qgemm_fused_kernel<<<grid, 256, 0, stream>>>(x, qw, scales, zeros, bias, out, M, N, K);
    }
}